// Round 2
// baseline (86.644 us; speedup 1.0000x reference)
//
#include <hip/hip_runtime.h>

#define N_IN_  1024
#define N_OUT_ 1536
#define N_CH   16

// Catmull-Rom-style cubic kernel, matching the reference formula in f32.
__device__ __forceinline__ float cubic_w(float x) {
    float ax = fabsf(x);
    float f1 = 1.0f + ax * ax * (1.5f * ax - 2.5f);
    float t  = 2.0f - ax;
    float f2 = -0.5f * (ax - 1.0f) * t * t;
    return ax <= 1.0f ? f1 : (ax < 2.0f ? f2 : 0.0f);
}

// j is the output index in pre-ifftshift space. Produces base tap index
// (i0 - 1) in INPUT index space (pre-fftshift) and the 4 tap weights.
__device__ __forceinline__ void axis_wts(int j, float* w, int& base) {
    const float c0 = -0.5f / 0.05f;                        // k_in[0]  = -10
    const float c1 = (-0.5f + 1.0f / 1023.0f) / 0.05f;     // k_in[1]
    const float h  = c1 - c0;
    float kout = (-0.5f + (float)j * (1.0f / 1535.0f)) / 0.15f;
    float u = (kout - c0) / h;                             // in [341, 682]
    int i0 = (int)floorf(u);
    base = i0 - 1;
    #pragma unroll
    for (int d = 0; d < 4; ++d)
        w[d] = cubic_w(u - (float)(base + d));
}

template <bool CPLX>
__global__ __launch_bounds__(256)
void resample_kernel(const float* __restrict__ re,
                     const float* __restrict__ im,
                     float* __restrict__ out) {
    const int x = blockIdx.x * 256 + threadIdx.x;   // output col
    const int y = blockIdx.y;                       // output row
    // ifftshift: which pre-shift output coordinate this pixel corresponds to
    const int jx = x < 768 ? x + 768 : x - 768;
    const int jy = y < 768 ? y + 768 : y - 768;

    float wx[4], wy[4];
    int bx, by;
    axis_wts(jx, wx, bx);
    axis_wts(jy, wy, by);
    // safety clamp (analysis says base in [339,681]; never binds meaningfully)
    bx = min(max(bx, 0), N_IN_ - 4);
    by = min(max(by, 0), N_IN_ - 4);

    // fold output scale RES_RATIO = 3.0 into wy
    #pragma unroll
    for (int d = 0; d < 4; ++d) wy[d] *= 3.0f;

    // combined 2D weights
    float w[4][4];
    #pragma unroll
    for (int dy = 0; dy < 4; ++dy)
        #pragma unroll
        for (int dx = 0; dx < 4; ++dx) w[dy][dx] = wy[dy] * wx[dx];

    // fftshift on input rows: mem row = (t + 512) % 1024
    int rofs[4];
    #pragma unroll
    for (int dy = 0; dy < 4; ++dy) {
        int t = by + dy;
        int r = (t >= 512) ? (t - 512) : (t + 512);
        rofs[dy] = r * N_IN_;
    }

    // fftshift on input cols: the 4 taps are contiguous in memory unless the
    // window straddles input index 511->512 (mem 1023->0). ~13/1536 columns.
    const bool hi = (bx >= 512);
    const bool lo = (bx + 3 < 512);
    const bool contig = hi || lo;
    const int xoff = hi ? (bx - 512) : (bx + 512);
    int cm[4];
    #pragma unroll
    for (int d = 0; d < 4; ++d) {
        int t = bx + d;
        cm[d] = (t >= 512) ? (t - 512) : (t + 512);
    }

    const int outbase = y * N_OUT_ + x;

    for (int c = 0; c < N_CH; ++c) {
        const float* rec = re + (size_t)c * (N_IN_ * N_IN_);
        float ar = 0.0f, ai = 0.0f;
        #pragma unroll
        for (int dy = 0; dy < 4; ++dy) {
            const float* rrow = rec + rofs[dy];
            float vr[4];
            if (contig) {
                __builtin_memcpy(vr, rrow + xoff, 16);
            } else {
                #pragma unroll
                for (int d = 0; d < 4; ++d) vr[d] = rrow[cm[d]];
            }
            #pragma unroll
            for (int d = 0; d < 4; ++d) ar = fmaf(w[dy][d], vr[d], ar);

            if (CPLX) {
                const float* irow = im + (size_t)c * (N_IN_ * N_IN_) + rofs[dy];
                float vi[4];
                if (contig) {
                    __builtin_memcpy(vi, irow + xoff, 16);
                } else {
                    #pragma unroll
                    for (int d = 0; d < 4; ++d) vi[d] = irow[cm[d]];
                }
                #pragma unroll
                for (int d = 0; d < 4; ++d) ai = fmaf(w[dy][d], vi[d], ai);
            }
        }
        if (CPLX) {
            float2* o2 = (float2*)out;
            o2[(size_t)c * (N_OUT_ * N_OUT_) + outbase] = make_float2(ar, ai);
        } else {
            out[(size_t)c * (N_OUT_ * N_OUT_) + outbase] = ar;
        }
    }
}

extern "C" void kernel_launch(void* const* d_in, const int* in_sizes, int n_in,
                              void* d_out, int out_size, void* d_ws, size_t ws_size,
                              hipStream_t stream) {
    const float* re = (const float*)d_in[0];   // kimage_real (16,1024,1024)
    const float* im = (const float*)d_in[1];   // kimage_imag (16,1024,1024)
    float* out = (float*)d_out;

    dim3 grid(N_OUT_ / 256, N_OUT_);
    // Harness casts the complex64 reference to float32 -> real part only,
    // out_size = 16*1536*1536. Branch defensively on the actual size in case
    // the output is instead interleaved complex (2x elements).
    if (out_size >= 2 * N_CH * N_OUT_ * N_OUT_) {
        resample_kernel<true><<<grid, dim3(256), 0, stream>>>(re, im, out);
    } else {
        resample_kernel<false><<<grid, dim3(256), 0, stream>>>(re, im, out);
    }
}

// Round 3
// 62.219 us; speedup vs baseline: 1.3926x; 1.3926x over previous
//
#include <hip/hip_runtime.h>

#define N_IN_   1024
#define N_OUT_  1536
#define N_CH    16
#define ROW0    340     // first input row/col index ever touched
#define N_ROWS  346     // rows 340..685 inclusive

// Catmull-Rom-style cubic kernel, matching the reference formula in f32.
__device__ __forceinline__ float cubic_w(float x) {
    float ax = fabsf(x);
    float f1 = 1.0f + ax * ax * (1.5f * ax - 2.5f);
    float t  = 2.0f - ax;
    float f2 = -0.5f * (ax - 1.0f) * t * t;
    return ax <= 1.0f ? f1 : (ax < 2.0f ? f2 : 0.0f);
}

// j = output index in pre-ifftshift space -> base tap index (i0-1) in input
// index space (pre-fftshift) and the 4 tap weights.
__device__ __forceinline__ void axis_wts(int j, float* w, int& base) {
    const float c0 = -0.5f / 0.05f;                        // k_in[0] = -10
    const float c1 = (-0.5f + 1.0f / 1023.0f) / 0.05f;     // k_in[1]
    const float h  = c1 - c0;
    float kout = (-0.5f + (float)j * (1.0f / 1535.0f)) / 0.15f;
    float u = (kout - c0) / h;                             // in [341, 682]
    int i0 = (int)floorf(u);
    base = i0 - 1;
    #pragma unroll
    for (int d = 0; d < 4; ++d)
        w[d] = cubic_w(u - (float)(base + d));
}

// ---------------- Pass 1: resample along x ----------------
// inter[c][ir][x] = 3 * sum_dx wx[dx] * in[c][memrow(ir+ROW0)][memcol(bx+dx)]
__global__ __launch_bounds__(256)
void pass1_x(const float* __restrict__ re, float* __restrict__ inter) {
    const int x  = blockIdx.x * 256 + threadIdx.x;  // final output col
    const int ir = blockIdx.y;                      // 0..N_ROWS-1
    const int jx = x < 768 ? x + 768 : x - 768;     // pre-ifftshift col

    float wx[4]; int bx;
    axis_wts(jx, wx, bx);
    bx = min(max(bx, 0), N_IN_ - 4);
    #pragma unroll
    for (int d = 0; d < 4; ++d) wx[d] *= 3.0f;      // fold RES_RATIO

    const int r    = ir + ROW0;
    const int rmem = (r >= 512) ? (r - 512) : (r + 512);   // fftshift row
    const size_t rbase = (size_t)rmem * N_IN_;

    // fftshift cols: contiguous unless window straddles idx 511->512
    const bool hi = (bx >= 512);
    const bool lo = (bx + 3 < 512);
    const bool contig = hi || lo;
    const int xoff = hi ? (bx - 512) : (bx + 512);
    int cm[4];
    #pragma unroll
    for (int d = 0; d < 4; ++d) {
        int t = bx + d;
        cm[d] = (t >= 512) ? (t - 512) : (t + 512);
    }

    for (int c = 0; c < N_CH; ++c) {
        const float* rrow = re + (size_t)c * (N_IN_ * N_IN_) + rbase;
        float v[4];
        if (contig) {
            __builtin_memcpy(v, rrow + xoff, 16);
        } else {
            #pragma unroll
            for (int d = 0; d < 4; ++d) v[d] = rrow[cm[d]];
        }
        float a = 0.0f;
        #pragma unroll
        for (int d = 0; d < 4; ++d) a = fmaf(wx[d], v[d], a);
        inter[((size_t)c * N_ROWS + ir) * N_OUT_ + x] = a;
    }
}

// ---------------- Pass 2: resample along y ----------------
__global__ __launch_bounds__(256)
void pass2_y(const float* __restrict__ inter, float* __restrict__ out) {
    const int x = blockIdx.x * 256 + threadIdx.x;
    const int y = blockIdx.y;
    const int jy = y < 768 ? y + 768 : y - 768;

    float wy[4]; int by;
    axis_wts(jy, wy, by);
    by = min(max(by, 0), N_IN_ - 4);
    int ir0 = by - ROW0;                            // 0..342, taps ir0..ir0+3
    ir0 = min(max(ir0, 0), N_ROWS - 4);

    const size_t ob = (size_t)y * N_OUT_ + x;
    for (int c = 0; c < N_CH; ++c) {
        const float* ib = inter + ((size_t)c * N_ROWS + ir0) * N_OUT_ + x;
        float a;
        a = wy[0] * ib[0];
        a = fmaf(wy[1], ib[1 * N_OUT_], a);
        a = fmaf(wy[2], ib[2 * N_OUT_], a);
        a = fmaf(wy[3], ib[3 * N_OUT_], a);
        out[(size_t)c * (N_OUT_ * N_OUT_) + ob] = a;
    }
}

// ---------------- Fallback: fused single-pass (proven R2 kernel) -------------
template <bool CPLX>
__global__ __launch_bounds__(256)
void resample_kernel(const float* __restrict__ re,
                     const float* __restrict__ im,
                     float* __restrict__ out) {
    const int x = blockIdx.x * 256 + threadIdx.x;
    const int y = blockIdx.y;
    const int jx = x < 768 ? x + 768 : x - 768;
    const int jy = y < 768 ? y + 768 : y - 768;

    float wx[4], wy[4];
    int bx, by;
    axis_wts(jx, wx, bx);
    axis_wts(jy, wy, by);
    bx = min(max(bx, 0), N_IN_ - 4);
    by = min(max(by, 0), N_IN_ - 4);

    #pragma unroll
    for (int d = 0; d < 4; ++d) wy[d] *= 3.0f;

    float w[4][4];
    #pragma unroll
    for (int dy = 0; dy < 4; ++dy)
        #pragma unroll
        for (int dx = 0; dx < 4; ++dx) w[dy][dx] = wy[dy] * wx[dx];

    int rofs[4];
    #pragma unroll
    for (int dy = 0; dy < 4; ++dy) {
        int t = by + dy;
        int r = (t >= 512) ? (t - 512) : (t + 512);
        rofs[dy] = r * N_IN_;
    }

    const bool hi = (bx >= 512);
    const bool lo = (bx + 3 < 512);
    const bool contig = hi || lo;
    const int xoff = hi ? (bx - 512) : (bx + 512);
    int cm[4];
    #pragma unroll
    for (int d = 0; d < 4; ++d) {
        int t = bx + d;
        cm[d] = (t >= 512) ? (t - 512) : (t + 512);
    }

    const int outbase = y * N_OUT_ + x;

    for (int c = 0; c < N_CH; ++c) {
        const float* rec = re + (size_t)c * (N_IN_ * N_IN_);
        float ar = 0.0f, ai = 0.0f;
        #pragma unroll
        for (int dy = 0; dy < 4; ++dy) {
            const float* rrow = rec + rofs[dy];
            float vr[4];
            if (contig) {
                __builtin_memcpy(vr, rrow + xoff, 16);
            } else {
                #pragma unroll
                for (int d = 0; d < 4; ++d) vr[d] = rrow[cm[d]];
            }
            #pragma unroll
            for (int d = 0; d < 4; ++d) ar = fmaf(w[dy][d], vr[d], ar);

            if (CPLX) {
                const float* irow = im + (size_t)c * (N_IN_ * N_IN_) + rofs[dy];
                float vi[4];
                if (contig) {
                    __builtin_memcpy(vi, irow + xoff, 16);
                } else {
                    #pragma unroll
                    for (int d = 0; d < 4; ++d) vi[d] = irow[cm[d]];
                }
                #pragma unroll
                for (int d = 0; d < 4; ++d) ai = fmaf(w[dy][d], vi[d], ai);
            }
        }
        if (CPLX) {
            float2* o2 = (float2*)out;
            o2[(size_t)c * (N_OUT_ * N_OUT_) + outbase] = make_float2(ar, ai);
        } else {
            out[(size_t)c * (N_OUT_ * N_OUT_) + outbase] = ar;
        }
    }
}

extern "C" void kernel_launch(void* const* d_in, const int* in_sizes, int n_in,
                              void* d_out, int out_size, void* d_ws, size_t ws_size,
                              hipStream_t stream) {
    const float* re = (const float*)d_in[0];   // kimage_real (16,1024,1024)
    const float* im = (const float*)d_in[1];   // kimage_imag (16,1024,1024)
    float* out = (float*)d_out;

    const size_t inter_bytes = (size_t)N_CH * N_ROWS * N_OUT_ * sizeof(float);

    if (out_size >= 2 * N_CH * N_OUT_ * N_OUT_) {
        // complex-interleaved output (defensive; not the observed case)
        dim3 grid(N_OUT_ / 256, N_OUT_);
        resample_kernel<true><<<grid, dim3(256), 0, stream>>>(re, im, out);
    } else if (ws_size >= inter_bytes) {
        float* inter = (float*)d_ws;
        pass1_x<<<dim3(N_OUT_ / 256, N_ROWS), dim3(256), 0, stream>>>(re, inter);
        pass2_y<<<dim3(N_OUT_ / 256, N_OUT_), dim3(256), 0, stream>>>(inter, out);
    } else {
        dim3 grid(N_OUT_ / 256, N_OUT_);
        resample_kernel<false><<<grid, dim3(256), 0, stream>>>(re, im, out);
    }
}